// Round 7
// baseline (65.038 us; speedup 1.0000x reference)
//
#include <hip/hip_runtime.h>
#include <math.h>

// Hausdorff distance, X[8192,3] vs Y[8192,3] fp32 — single fused kernel.
// d2(i,j) = |a_i|^2 - 2*max_term, max_term = max_j (a_i . b_j - |b_j|^2/2).
// 512 blocks: each computes per-row min-d2 over its 128-col chunk (LDS float4
// broadcast + packed fp32 FMA), atomicMin's into a 16K-entry min buffer, then
// the last-finished block (atomic counter) max-reduces + sqrt -> out.
// Init: two hipMemsetAsync nodes (0x7F sentinel = 3.39e38; counter = 0).

typedef float v2f __attribute__((ext_vector_type(2)));

constexpr int NPTS = 8192;
constexpr int T = 256;             // threads per block
constexpr int R = 8;               // rows per thread (4 float2 groups)
constexpr int ROWS_PB = T * R;     // 2048
constexpr int RG = NPTS / ROWS_PB; // 4 row groups
constexpr int CG = 64;             // col chunks per direction
constexpr int COLS = NPTS / CG;    // 128 B-points per block
constexpr int NBLK = 2 * RG * CG;  // 512 blocks

__global__ __launch_bounds__(T) void hausdorff_fused_kernel(
        const float* __restrict__ X, const float* __restrict__ Y,
        unsigned* __restrict__ minbuf,   // [2*NPTS], preset to 0x7F7F7F7F
        unsigned* __restrict__ counter,  // [1], preset to 0
        float* __restrict__ out) {
    int b = blockIdx.x;
    int dir = b / (RG * CG);
    int rem = b - dir * (RG * CG);
    int rg = rem / CG;
    int cg = rem - rg * CG;
    const float* A = dir ? Y : X;
    const float* B = dir ? X : Y;

    int t = threadIdx.x;
    int r0 = rg * ROWS_PB + t;

    // A rows -> registers (issue early; latency hides under staging)
    float ax[R], ay[R], az[R];
#pragma unroll
    for (int k = 0; k < R; ++k) {
        int row = r0 + k * T;
        ax[k] = A[row * 3 + 0];
        ay[k] = A[row * 3 + 1];
        az[k] = A[row * 3 + 2];
    }

    // Stage B chunk as (x, y, z, -0.5*|b|^2)
    __shared__ float4 Bs[COLS];
    for (int i = t; i < COLS; i += T) {
        int j = cg * COLS + i;
        float bx = B[j * 3 + 0], by = B[j * 3 + 1], bz = B[j * 3 + 2];
        Bs[i] = make_float4(bx, by, bz, -0.5f * fmaf(bx, bx, fmaf(by, by, bz * bz)));
    }

    v2f ax2[R / 2], ay2[R / 2], az2[R / 2], na2[R / 2], mt2[R / 2];
#pragma unroll
    for (int q = 0; q < R / 2; ++q) {
        ax2[q] = (v2f){ax[2 * q], ax[2 * q + 1]};
        ay2[q] = (v2f){ay[2 * q], ay[2 * q + 1]};
        az2[q] = (v2f){az[2 * q], az[2 * q + 1]};
        na2[q] = ax2[q] * ax2[q] + ay2[q] * ay2[q] + az2[q] * az2[q];
        mt2[q] = (v2f){-__builtin_inff(), -__builtin_inff()};
    }
    __syncthreads();

#pragma unroll 8
    for (int j = 0; j < COLS; ++j) {
        float4 p = Bs[j];  // wave-uniform -> ds_read_b128 broadcast, 0 conflicts
        v2f px = (v2f){p.x, p.x};
        v2f py = (v2f){p.y, p.y};
        v2f pz = (v2f){p.z, p.z};
        v2f pw = (v2f){p.w, p.w};
#pragma unroll
        for (int q = 0; q < R / 2; ++q) {
            v2f tt = az2[q] * pz + pw;   // fp-contract -> v_pk_fma_f32
            tt = ay2[q] * py + tt;
            tt = ax2[q] * px + tt;
            mt2[q].x = fmaxf(mt2[q].x, tt.x);
            mt2[q].y = fmaxf(mt2[q].y, tt.y);
        }
    }

    // per-row chunk-min -> device atomicMin (non-negative float bits order
    // as unsigned; clamp to 0 so bit-ordering is safe)
    unsigned* om = minbuf + dir * NPTS + rg * ROWS_PB + t;
#pragma unroll
    for (int q = 0; q < R / 2; ++q) {
        float d0 = fmaxf(fmaf(-2.f, mt2[q].x, na2[q].x), 0.f);
        float d1 = fmaxf(fmaf(-2.f, mt2[q].y, na2[q].y), 0.f);
        atomicMin(&om[(2 * q) * T], __float_as_uint(d0));
        atomicMin(&om[(2 * q + 1) * T], __float_as_uint(d1));
    }

    // elect the last block to finish
    __threadfence();  // release: mins visible before counter bump
    __shared__ unsigned is_last;
    if (t == 0) is_last = (atomicAdd(counter, 1u) == NBLK - 1) ? 1u : 0u;
    __syncthreads();
    if (!is_last) return;

    __threadfence();  // acquire
    float mx = 0.f;
    for (int i = t; i < 2 * NPTS; i += T) {
        unsigned u = __hip_atomic_load(&minbuf[i], __ATOMIC_RELAXED,
                                       __HIP_MEMORY_SCOPE_AGENT);
        mx = fmaxf(mx, __uint_as_float(u));
    }
    for (int o = 32; o > 0; o >>= 1) mx = fmaxf(mx, __shfl_down(mx, o));
    __shared__ float wm[T / 64];
    if ((t & 63) == 0) wm[t >> 6] = mx;
    __syncthreads();
    if (t == 0) {
        float mm = wm[0];
        for (int w = 1; w < T / 64; ++w) mm = fmaxf(mm, wm[w]);
        out[0] = sqrtf(mm);
    }
}

// ---------- fallback (ws too small even for minbuf): 3-dispatch path ----------

constexpr int SEG_J = 512;
constexpr int SEGS = NPTS / SEG_J;

__global__ void init_min_kernel(unsigned* wsmin, int n) {
    int i = blockIdx.x * blockDim.x + threadIdx.x;
    if (i < n) wsmin[i] = 0x7F800000u;
}

__global__ __launch_bounds__(T) void pair_min_kernel(
        const float* __restrict__ X, const float* __restrict__ Y,
        unsigned* __restrict__ minXY, unsigned* __restrict__ minYX) {
    constexpr int RPB = T * 8;
    constexpr int BLOCKS_PER_DIR = (NPTS / RPB) * SEGS;
    int b = blockIdx.x;
    int dir = b / BLOCKS_PER_DIR;
    int rem = b - dir * BLOCKS_PER_DIR;
    int rg = rem / SEGS;
    int seg = rem - rg * SEGS;
    const float* A = dir ? Y : X;
    const float* B = dir ? X : Y;
    unsigned* omin = dir ? minYX : minXY;

    __shared__ float Bs[SEG_J * 3];
    int t = threadIdx.x;
    const float* Bseg = B + seg * SEG_J * 3;
    for (int i = t; i < SEG_J * 3; i += T) Bs[i] = Bseg[i];

    int r0 = rg * RPB + t;
    float ax[8], ay[8], az[8], m[8];
#pragma unroll
    for (int r = 0; r < 8; ++r) {
        int row = r0 + r * T;
        ax[r] = A[row * 3 + 0];
        ay[r] = A[row * 3 + 1];
        az[r] = A[row * 3 + 2];
        m[r] = __builtin_inff();
    }
    __syncthreads();

#pragma unroll 2
    for (int j = 0; j < SEG_J; ++j) {
        float bx = Bs[3 * j + 0], by = Bs[3 * j + 1], bz = Bs[3 * j + 2];
#pragma unroll
        for (int r = 0; r < 8; ++r) {
            float dx = ax[r] - bx, dy = ay[r] - by, dz = az[r] - bz;
            m[r] = fminf(m[r], fmaf(dx, dx, fmaf(dy, dy, dz * dz)));
        }
    }
#pragma unroll
    for (int r = 0; r < 8; ++r)
        atomicMin(&omin[r0 + r * T], __float_as_uint(m[r]));
}

__global__ __launch_bounds__(T) void finalize_min_kernel(
        const unsigned* __restrict__ wsmin, float* __restrict__ out, int n) {
    int t = threadIdx.x;
    float mx = 0.f;
    for (int i = t; i < n; i += T) mx = fmaxf(mx, __uint_as_float(wsmin[i]));
    for (int o = 32; o > 0; o >>= 1) mx = fmaxf(mx, __shfl_down(mx, o));
    __shared__ float wmax[T / 64];
    if ((t & 63) == 0) wmax[t >> 6] = mx;
    __syncthreads();
    if (t == 0) {
        float mm = wmax[0];
        for (int w = 1; w < T / 64; ++w) mm = fmaxf(mm, wmax[w]);
        out[0] = sqrtf(mm);
    }
}

extern "C" void kernel_launch(void* const* d_in, const int* in_sizes, int n_in,
                              void* d_out, int out_size, void* d_ws, size_t ws_size,
                              hipStream_t stream) {
    const float* X = (const float*)d_in[0];
    const float* Y = (const float*)d_in[1];
    float* out = (float*)d_out;

    const size_t minbuf_bytes = (size_t)2 * NPTS * sizeof(unsigned);

    if (ws_size >= minbuf_bytes + sizeof(unsigned)) {
        unsigned* minbuf = (unsigned*)d_ws;
        unsigned* counter = (unsigned*)((char*)d_ws + minbuf_bytes);
        // 0x7F7F7F7F == 3.39e38f sentinel (> any d2); counter = 0
        hipMemsetAsync(minbuf, 0x7F, minbuf_bytes, stream);
        hipMemsetAsync(counter, 0, sizeof(unsigned), stream);
        hausdorff_fused_kernel<<<NBLK, T, 0, stream>>>(X, Y, minbuf, counter, out);
    } else if (ws_size >= minbuf_bytes) {
        unsigned* wsmin = (unsigned*)d_ws;
        init_min_kernel<<<(2 * NPTS + T - 1) / T, T, 0, stream>>>(wsmin, 2 * NPTS);
        pair_min_kernel<<<2 * (NPTS / (T * 8)) * SEGS, T, 0, stream>>>(
            X, Y, wsmin, wsmin + NPTS);
        finalize_min_kernel<<<1, T, 0, stream>>>(wsmin, out, 2 * NPTS);
    }
}

// Round 8
// 26.894 us; speedup vs baseline: 2.4183x; 2.4183x over previous
//
#include <hip/hip_runtime.h>
#include <math.h>

// Hausdorff distance, X[8192,3] vs Y[8192,3] fp32.
// d2(i,j) = |a_i|^2 - 2*max_term, max_term = max_j (a_i . b_j - |b_j|^2/2).
// Rows packed as float2 -> v_pk_fma_f32 (2.5 VALU instr/pair).
// R=16 rows/thread: each broadcast ds_read_b128 feeds 16 rows of math
// (LDS pipe per-CU @ ~12cy/b128 was the R<=8 bottleneck).
// 3 dispatches, NO hot atomics:
//   pair<512,16,128>: 256 blocks (1/CU), partial min per (row, colchunk)
//   reduce<128>:      64 blocks, 16-accumulator strided min + row max
//   final:            1 block, max of 64 + sqrt

typedef float v2f __attribute__((ext_vector_type(2)));

constexpr int NPTS = 8192;

template <int TT, int RR, int CGN>
__global__ __launch_bounds__(TT) void pair_partial_kernel(
        const float* __restrict__ X, const float* __restrict__ Y,
        float* __restrict__ partial) {
    constexpr int ROWS_PB = TT * RR;
    constexpr int RG = NPTS / ROWS_PB;
    constexpr int COLS = NPTS / CGN;

    int b = blockIdx.x;
    int dir = b / (RG * CGN);
    int rem = b - dir * (RG * CGN);
    int rg = rem / CGN;
    int cg = rem - rg * CGN;
    const float* A = dir ? Y : X;
    const float* B = dir ? X : Y;

    int t = threadIdx.x;
    int r0 = rg * ROWS_PB + t;

    // A rows -> packed registers (issued early; latency hides under staging)
    v2f ax2[RR / 2], ay2[RR / 2], az2[RR / 2], na2[RR / 2], mt2[RR / 2];
#pragma unroll
    for (int q = 0; q < RR / 2; ++q) {
        int ra = r0 + (2 * q) * TT;
        int rb = r0 + (2 * q + 1) * TT;
        ax2[q] = (v2f){A[ra * 3 + 0], A[rb * 3 + 0]};
        ay2[q] = (v2f){A[ra * 3 + 1], A[rb * 3 + 1]};
        az2[q] = (v2f){A[ra * 3 + 2], A[rb * 3 + 2]};
    }

    // Stage B chunk as (x, y, z, -0.5*|b|^2)
    __shared__ float4 Bs[COLS];
    for (int i = t; i < COLS; i += TT) {
        int j = cg * COLS + i;
        float bx = B[j * 3 + 0], by = B[j * 3 + 1], bz = B[j * 3 + 2];
        Bs[i] = make_float4(bx, by, bz, -0.5f * fmaf(bx, bx, fmaf(by, by, bz * bz)));
    }

#pragma unroll
    for (int q = 0; q < RR / 2; ++q) {
        na2[q] = ax2[q] * ax2[q] + ay2[q] * ay2[q] + az2[q] * az2[q];
        mt2[q] = (v2f){-__builtin_inff(), -__builtin_inff()};
    }
    __syncthreads();

#pragma unroll 8
    for (int j = 0; j < COLS; ++j) {
        float4 p = Bs[j];  // wave-uniform -> ds_read_b128 broadcast, 0 conflicts
        v2f px = (v2f){p.x, p.x};
        v2f py = (v2f){p.y, p.y};
        v2f pz = (v2f){p.z, p.z};
        v2f pw = (v2f){p.w, p.w};
#pragma unroll
        for (int q = 0; q < RR / 2; ++q) {
            v2f tt = az2[q] * pz + pw;   // fp-contract -> v_pk_fma_f32
            tt = ay2[q] * py + tt;
            tt = ax2[q] * px + tt;
            mt2[q].x = fmaxf(mt2[q].x, tt.x);
            mt2[q].y = fmaxf(mt2[q].y, tt.y);
        }
    }

    // partial d2-min for this col chunk; coalesced stores
    float* op = partial + (size_t)(dir * CGN + cg) * NPTS + rg * ROWS_PB + t;
#pragma unroll
    for (int q = 0; q < RR / 2; ++q) {
        op[(2 * q) * TT]     = fmaf(-2.f, mt2[q].x, na2[q].x);
        op[(2 * q + 1) * TT] = fmaf(-2.f, mt2[q].y, na2[q].y);
    }
}

template <int CGN>
__global__ __launch_bounds__(256) void reduce_kernel(
        const float* __restrict__ partial, float* __restrict__ blockmax) {
    constexpr int NACC = (CGN >= 16) ? 16 : 8;
    int rid = blockIdx.x * 256 + threadIdx.x;  // 0..16383
    int dir = rid >> 13;
    int row = rid & (NPTS - 1);
    const float* p = partial + (size_t)dir * CGN * NPTS + row;

    float m[NACC];
#pragma unroll
    for (int k = 0; k < NACC; ++k) m[k] = __builtin_inff();
#pragma unroll
    for (int cg = 0; cg < CGN; ++cg)
        m[cg & (NACC - 1)] = fminf(m[cg & (NACC - 1)], p[(size_t)cg * NPTS]);
#pragma unroll
    for (int s = NACC / 2; s > 0; s >>= 1)
#pragma unroll
        for (int k = 0; k < s; ++k) m[k] = fminf(m[k], m[k + s]);

    float mm = fmaxf(m[0], 0.f);  // dot-form can dip slightly negative
    for (int o = 32; o > 0; o >>= 1) mm = fmaxf(mm, __shfl_down(mm, o));
    __shared__ float wm[4];
    if ((threadIdx.x & 63) == 0) wm[threadIdx.x >> 6] = mm;
    __syncthreads();
    if (threadIdx.x == 0) {
        float bm = fmaxf(fmaxf(wm[0], wm[1]), fmaxf(wm[2], wm[3]));
        blockmax[blockIdx.x] = bm;
    }
}

__global__ void final_kernel(const float* __restrict__ blockmax,
                             float* __restrict__ out, int n) {
    float m = blockmax[threadIdx.x < n ? threadIdx.x : 0];
    for (int o = 32; o > 0; o >>= 1) m = fmaxf(m, __shfl_down(m, o));
    if (threadIdx.x == 0) out[0] = sqrtf(m);
}

// ---------- last-resort fallback (tiny ws): atomic version ----------

__global__ void init_min_kernel(unsigned* wsmin, int n) {
    int i = blockIdx.x * blockDim.x + threadIdx.x;
    if (i < n) wsmin[i] = 0x7F800000u;
}

__global__ __launch_bounds__(256) void pair_min_kernel(
        const float* __restrict__ X, const float* __restrict__ Y,
        unsigned* __restrict__ minXY, unsigned* __restrict__ minYX) {
    constexpr int SEG_J = 512;
    constexpr int SEGS = NPTS / SEG_J;
    constexpr int RPB = 256 * 8;
    constexpr int BLOCKS_PER_DIR = (NPTS / RPB) * SEGS;
    int b = blockIdx.x;
    int dir = b / BLOCKS_PER_DIR;
    int rem = b - dir * BLOCKS_PER_DIR;
    int rg = rem / SEGS;
    int seg = rem - rg * SEGS;
    const float* A = dir ? Y : X;
    const float* B = dir ? X : Y;
    unsigned* omin = dir ? minYX : minXY;

    __shared__ float Bs[SEG_J * 3];
    int t = threadIdx.x;
    const float* Bseg = B + seg * SEG_J * 3;
    for (int i = t; i < SEG_J * 3; i += 256) Bs[i] = Bseg[i];

    int r0 = rg * RPB + t;
    float ax[8], ay[8], az[8], m[8];
#pragma unroll
    for (int r = 0; r < 8; ++r) {
        int row = r0 + r * 256;
        ax[r] = A[row * 3 + 0];
        ay[r] = A[row * 3 + 1];
        az[r] = A[row * 3 + 2];
        m[r] = __builtin_inff();
    }
    __syncthreads();

#pragma unroll 2
    for (int j = 0; j < SEG_J; ++j) {
        float bx = Bs[3 * j + 0], by = Bs[3 * j + 1], bz = Bs[3 * j + 2];
#pragma unroll
        for (int r = 0; r < 8; ++r) {
            float dx = ax[r] - bx, dy = ay[r] - by, dz = az[r] - bz;
            m[r] = fminf(m[r], fmaf(dx, dx, fmaf(dy, dy, dz * dz)));
        }
    }
#pragma unroll
    for (int r = 0; r < 8; ++r)
        atomicMin(&omin[r0 + r * 256], __float_as_uint(m[r]));
}

__global__ __launch_bounds__(256) void finalize_min_kernel(
        const unsigned* __restrict__ wsmin, float* __restrict__ out, int n) {
    int t = threadIdx.x;
    float mx = 0.f;
    for (int i = t; i < n; i += 256) mx = fmaxf(mx, __uint_as_float(wsmin[i]));
    for (int o = 32; o > 0; o >>= 1) mx = fmaxf(mx, __shfl_down(mx, o));
    __shared__ float wmax[4];
    if ((t & 63) == 0) wmax[t >> 6] = mx;
    __syncthreads();
    if (t == 0) {
        float mm = fmaxf(fmaxf(wmax[0], wmax[1]), fmaxf(wmax[2], wmax[3]));
        out[0] = sqrtf(mm);
    }
}

extern "C" void kernel_launch(void* const* d_in, const int* in_sizes, int n_in,
                              void* d_out, int out_size, void* d_ws, size_t ws_size,
                              hipStream_t stream) {
    const float* X = (const float*)d_in[0];
    const float* Y = (const float*)d_in[1];
    float* out = (float*)d_out;

    const size_t need128 = (size_t)(2 * 128 * NPTS + 64) * sizeof(float);
    const size_t need64  = (size_t)(2 * 64  * NPTS + 64) * sizeof(float);

    if (ws_size >= need128) {
        // T=512, R=16, CG=128: 256 blocks (1/CU), LDS reads amortized 16x
        float* partial = (float*)d_ws;
        float* blockmax = partial + 2 * 128 * NPTS;
        pair_partial_kernel<512, 16, 128><<<256, 512, 0, stream>>>(X, Y, partial);
        reduce_kernel<128><<<2 * NPTS / 256, 256, 0, stream>>>(partial, blockmax);
        final_kernel<<<1, 64, 0, stream>>>(blockmax, out, 2 * NPTS / 256);
    } else if (ws_size >= need64) {
        // proven R6 config as fallback
        float* partial = (float*)d_ws;
        float* blockmax = partial + 2 * 64 * NPTS;
        pair_partial_kernel<256, 8, 64><<<512, 256, 0, stream>>>(X, Y, partial);
        reduce_kernel<64><<<2 * NPTS / 256, 256, 0, stream>>>(partial, blockmax);
        final_kernel<<<1, 64, 0, stream>>>(blockmax, out, 2 * NPTS / 256);
    } else if (ws_size >= 2 * NPTS * sizeof(unsigned)) {
        unsigned* wsmin = (unsigned*)d_ws;
        init_min_kernel<<<(2 * NPTS + 255) / 256, 256, 0, stream>>>(wsmin, 2 * NPTS);
        pair_min_kernel<<<2 * (NPTS / (256 * 8)) * (NPTS / 512), 256, 0, stream>>>(
            X, Y, wsmin, wsmin + NPTS);
        finalize_min_kernel<<<1, 256, 0, stream>>>(wsmin, out, 2 * NPTS);
    }
}